// Round 2
// baseline (730.536 us; speedup 1.0000x reference)
//
#include <hip/hip_runtime.h>

// GCN 2-layer: N=65536 nodes, E=1048576 edges, 128 -> 64 -> 64, fp32.
// Pipeline:
//   deg (atomic hist) -> dinv = rsqrt(deg+1)
//   P1 = dinv * (x @ W1); A1 = P1 (self loop)
//   A1[dst] += P1[src]  (edge scatter, atomics)
//   H = relu(dinv * A1 + b1)        (in-place on A1)
//   P2 = dinv * (H @ W2); out = P2  (self loop, init d_out)
//   out[dst] += P2[src]
//   out = dinv * out + b2

#define N_NODES 65536
#define E_EDGES 1048576
#define F_IN    128
#define F_HID   64
#define F_OUT   64

__global__ void k_degree(const int* __restrict__ dst, float* __restrict__ deg) {
    int i = blockIdx.x * blockDim.x + threadIdx.x;
    int stride = gridDim.x * blockDim.x;
    for (int e = i; e < E_EDGES; e += stride)
        atomicAdd(&deg[dst[e]], 1.0f);
}

__global__ void k_dinv(float* __restrict__ deg) {
    int v = blockIdx.x * blockDim.x + threadIdx.x;
    if (v < N_NODES) deg[v] = rsqrtf(deg[v] + 1.0f);  // +1 = self loop
}

// One 64-lane group per node; lane j computes output column j.
// W (F_K x 64) staged in LDS. Writes P[v] = dinv[v]*(h@W) and A[v] = P[v].
template <int F_K>
__global__ void k_gemm_scale(const float* __restrict__ h, const float* __restrict__ W,
                             const float* __restrict__ dinv,
                             float* __restrict__ P, float* __restrict__ A) {
    __shared__ float Wl[F_K * 64];
    for (int i = threadIdx.x; i < F_K * 64; i += blockDim.x) Wl[i] = W[i];
    __syncthreads();
    int lane = threadIdx.x & 63;
    int grp  = (blockIdx.x * blockDim.x + threadIdx.x) >> 6;
    int ngrp = (gridDim.x * blockDim.x) >> 6;
    for (int v = grp; v < N_NODES; v += ngrp) {
        const float* hr = h + (size_t)v * F_K;
        float acc = 0.0f;
#pragma unroll 8
        for (int k = 0; k < F_K; ++k)
            acc = fmaf(hr[k], Wl[k * 64 + lane], acc);
        float val = acc * dinv[v];
        size_t o = (size_t)v * 64 + lane;
        P[o] = val;
        A[o] = val;
    }
}

// Per edge: A[dst] += P[src] across 64 columns (one 64-lane group per edge).
__global__ void k_scatter(const int* __restrict__ src, const int* __restrict__ dst,
                          const float* __restrict__ P, float* __restrict__ A) {
    int lane = threadIdx.x & 63;
    int grp  = (blockIdx.x * blockDim.x + threadIdx.x) >> 6;
    int ngrp = (gridDim.x * blockDim.x) >> 6;
    for (int e = grp; e < E_EDGES; e += ngrp) {
        int s = src[e], d = dst[e];
        atomicAdd(&A[(size_t)d * 64 + lane], P[(size_t)s * 64 + lane]);
    }
}

// A[v][j] = relu(dinv[v]*A[v][j] + b[j])   (layer 1, in place)
__global__ void k_finish_relu(float* __restrict__ A, const float* __restrict__ dinv,
                              const float* __restrict__ b) {
    int i = blockIdx.x * blockDim.x + threadIdx.x;
    int total = N_NODES * 64;
    int stride = gridDim.x * blockDim.x;
    for (int t = i; t < total; t += stride) {
        int v = t >> 6, j = t & 63;
        float val = dinv[v] * A[t] + b[j];
        A[t] = val > 0.0f ? val : 0.0f;
    }
}

// out[v][j] = dinv[v]*out[v][j] + b[j]     (layer 2, in place)
__global__ void k_finish(float* __restrict__ A, const float* __restrict__ dinv,
                         const float* __restrict__ b) {
    int i = blockIdx.x * blockDim.x + threadIdx.x;
    int total = N_NODES * 64;
    int stride = gridDim.x * blockDim.x;
    for (int t = i; t < total; t += stride) {
        int v = t >> 6, j = t & 63;
        A[t] = dinv[v] * A[t] + b[j];
    }
}

extern "C" void kernel_launch(void* const* d_in, const int* in_sizes, int n_in,
                              void* d_out, int out_size, void* d_ws, size_t ws_size,
                              hipStream_t stream) {
    const float* x   = (const float*)d_in[0];
    const int*   ei  = (const int*)d_in[1];      // [2, E]: src row, dst row
    const float* W1  = (const float*)d_in[2];
    const float* b1  = (const float*)d_in[3];
    const float* W2  = (const float*)d_in[4];
    const float* b2  = (const float*)d_in[5];
    float*       out = (float*)d_out;

    const int* src = ei;
    const int* dst = ei + E_EDGES;

    float* dinv = (float*)d_ws;                         // N floats
    float* bufA = dinv + N_NODES;                       // N*64: P1 then P2
    float* bufB = bufA + (size_t)N_NODES * 64;          // N*64: A1 then H

    // deg = 0; histogram; dinv = rsqrt(deg+1)
    hipMemsetAsync(dinv, 0, N_NODES * sizeof(float), stream);
    k_degree<<<1024, 256, 0, stream>>>(dst, dinv);
    k_dinv<<<N_NODES / 256, 256, 0, stream>>>(dinv);

    // Layer 1
    k_gemm_scale<F_IN><<<2048, 256, 0, stream>>>(x, W1, dinv, bufA, bufB);
    k_scatter<<<4096, 256, 0, stream>>>(src, dst, bufA, bufB);
    k_finish_relu<<<2048, 256, 0, stream>>>(bufB, dinv, b1);

    // Layer 2 (d_out is the accumulator)
    k_gemm_scale<F_HID><<<2048, 256, 0, stream>>>(bufB, W2, dinv, bufA, out);
    k_scatter<<<4096, 256, 0, stream>>>(src, dst, bufA, out);
    k_finish<<<2048, 256, 0, stream>>>(out, dinv, b2);
}

// Round 3
// 451.495 us; speedup vs baseline: 1.6180x; 1.6180x over previous
//
#include <hip/hip_runtime.h>

// GCN 2-layer, CSR-based (no fp32 atomics in the hot path).
//   counts[v] = # incoming edges (int hist)
//   cursor    = exclusive prefix of counts; dinv = rsqrt(counts+1)
//   csr[pos]  = src, grouped by dst (fill advances cursor to end-of-row)
//   P = dinv * (h @ W)                        (per layer)
//   out[v] = act(dinv[v] * (P[v] + sum_{e->v} P[src]) + b)
// Layer-1 output H lives in d_out (overwritten by layer 2's result).

#define N_NODES 65536
#define E_EDGES 1048576
#define F_IN    128
#define F_HID   64

__global__ void k_hist(const int* __restrict__ dst, int* __restrict__ counts) {
    int i = blockIdx.x * blockDim.x + threadIdx.x;
    int stride = gridDim.x * blockDim.x;
    for (int e = i; e < E_EDGES; e += stride)
        atomicAdd(&counts[dst[e]], 1);
}

// One block, 1024 threads. Exclusive scan of counts -> cursor; dinv = rsqrt(c+1).
__global__ void k_scan(const int* __restrict__ counts, int* __restrict__ cursor,
                       float* __restrict__ dinv) {
    __shared__ int part[1024];
    int t = threadIdx.x;
    int base = t * 64;
    int s = 0;
    for (int i = 0; i < 64; ++i) s += counts[base + i];
    part[t] = s;
    __syncthreads();
    for (int off = 1; off < 1024; off <<= 1) {
        int val = (t >= off) ? part[t - off] : 0;
        __syncthreads();
        part[t] += val;
        __syncthreads();
    }
    int run = (t > 0) ? part[t - 1] : 0;   // exclusive offset of this thread's chunk
    for (int i = 0; i < 64; ++i) {
        int c = counts[base + i];
        cursor[base + i] = run;            // row start; k_fill advances to row end
        dinv[base + i] = rsqrtf((float)c + 1.0f);
        run += c;
    }
}

// Scatter src ids into CSR slots. Afterwards cursor[v] == row end.
__global__ void k_fill(const int* __restrict__ src, const int* __restrict__ dst,
                       int* __restrict__ cursor, int* __restrict__ csr) {
    int i = blockIdx.x * blockDim.x + threadIdx.x;
    int stride = gridDim.x * blockDim.x;
    for (int e = i; e < E_EDGES; e += stride) {
        int pos = atomicAdd(&cursor[dst[e]], 1);
        csr[pos] = src[e];
    }
}

// One 64-lane group per node; lane j = output column j. W staged in LDS.
// P[v] = dinv[v] * (h[v] @ W)
template <int F_K>
__global__ void k_gemm_scale(const float* __restrict__ h, const float* __restrict__ W,
                             const float* __restrict__ dinv, float* __restrict__ P) {
    __shared__ float Wl[F_K * 64];
    for (int i = threadIdx.x; i < F_K * 64; i += blockDim.x) Wl[i] = W[i];
    __syncthreads();
    int lane = threadIdx.x & 63;
    int grp  = (blockIdx.x * blockDim.x + threadIdx.x) >> 6;
    int ngrp = (gridDim.x * blockDim.x) >> 6;
    for (int v = grp; v < N_NODES; v += ngrp) {
        const float* hr = h + (size_t)v * F_K;
        float acc = 0.0f;
#pragma unroll 8
        for (int k = 0; k < F_K; ++k)
            acc = fmaf(hr[k], Wl[k * 64 + lane], acc);
        P[(size_t)v * 64 + lane] = acc * dinv[v];
    }
}

// One 64-lane group per node: register-accumulate gathered P rows, write once.
template <bool RELU>
__global__ void k_aggregate(const float* __restrict__ P, const int* __restrict__ csr,
                            const int* __restrict__ cursor, const int* __restrict__ counts,
                            const float* __restrict__ dinv, const float* __restrict__ b,
                            float* __restrict__ out) {
    int lane = threadIdx.x & 63;
    int grp  = (blockIdx.x * blockDim.x + threadIdx.x) >> 6;
    int ngrp = (gridDim.x * blockDim.x) >> 6;
    float bias = b[lane];
    for (int v = grp; v < N_NODES; v += ngrp) {
        int end = cursor[v];
        int beg = end - counts[v];
        float acc = P[(size_t)v * 64 + lane];      // self loop
        int i = beg;
        for (; i + 3 < end; i += 4) {              // 4-deep ILP on the gather
            int s0 = csr[i], s1 = csr[i + 1], s2 = csr[i + 2], s3 = csr[i + 3];
            float p0 = P[(size_t)s0 * 64 + lane];
            float p1 = P[(size_t)s1 * 64 + lane];
            float p2 = P[(size_t)s2 * 64 + lane];
            float p3 = P[(size_t)s3 * 64 + lane];
            acc += (p0 + p1) + (p2 + p3);
        }
        for (; i < end; ++i)
            acc += P[(size_t)csr[i] * 64 + lane];
        float val = dinv[v] * acc + bias;
        if (RELU) val = val > 0.0f ? val : 0.0f;
        out[(size_t)v * 64 + lane] = val;
    }
}

extern "C" void kernel_launch(void* const* d_in, const int* in_sizes, int n_in,
                              void* d_out, int out_size, void* d_ws, size_t ws_size,
                              hipStream_t stream) {
    const float* x   = (const float*)d_in[0];
    const int*   ei  = (const int*)d_in[1];      // [2, E]: src row, dst row
    const float* W1  = (const float*)d_in[2];
    const float* b1  = (const float*)d_in[3];
    const float* W2  = (const float*)d_in[4];
    const float* b2  = (const float*)d_in[5];
    float*       out = (float*)d_out;

    const int* src = ei;
    const int* dst = ei + E_EDGES;

    float* dinv   = (float*)d_ws;                          // N floats
    int*   counts = (int*)(dinv + N_NODES);                // N ints
    int*   cursor = counts + N_NODES;                      // N ints
    int*   csr    = cursor + N_NODES;                      // E ints
    float* P      = (float*)(csr + E_EDGES);               // N*64 floats
    float* H      = out;                                   // layer-1 output lives in d_out

    // CSR build
    hipMemsetAsync(counts, 0, N_NODES * sizeof(int), stream);
    k_hist<<<1024, 256, 0, stream>>>(dst, counts);
    k_scan<<<1, 1024, 0, stream>>>(counts, cursor, dinv);
    k_fill<<<1024, 256, 0, stream>>>(src, dst, cursor, csr);

    // Layer 1: x -> H (relu)
    k_gemm_scale<F_IN><<<2048, 256, 0, stream>>>(x, W1, dinv, P);
    k_aggregate<true><<<2048, 256, 0, stream>>>(P, csr, cursor, counts, dinv, b1, H);

    // Layer 2: H -> out
    k_gemm_scale<F_HID><<<2048, 256, 0, stream>>>(H, W2, dinv, P);
    k_aggregate<false><<<2048, 256, 0, stream>>>(P, csr, cursor, counts, dinv, b2, out);
}

// Round 4
// 396.818 us; speedup vs baseline: 1.8410x; 1.1378x over previous
//
#include <hip/hip_runtime.h>

// GCN 2-layer, CSR-based (no fp32 atomics in the hot path).
//   counts[v] = # incoming edges (int hist)
//   cursor    = exclusive prefix of counts; dinv = rsqrt(counts+1)
//   csr[pos]  = src, grouped by dst (fill advances cursor to end-of-row)
//   P = dinv * (h @ W)                        (per layer)
//   out[v] = act(dinv[v] * (P[v] + sum_{e->v} P[src]) + b)
// GEMM: one thread per node, acc[64] in VGPRs, W read via wave-uniform
// indices -> scalar cache (s_load), h via per-lane float4. No LDS.

#define N_NODES 65536
#define E_EDGES 1048576
#define F_IN    128
#define F_HID   64

__global__ void k_hist(const int* __restrict__ dst, int* __restrict__ counts) {
    int i = blockIdx.x * blockDim.x + threadIdx.x;
    int stride = gridDim.x * blockDim.x;
    for (int e = i; e < E_EDGES; e += stride)
        atomicAdd(&counts[dst[e]], 1);
}

// One block, 1024 threads. Exclusive scan of counts -> cursor; dinv = rsqrt(c+1).
__global__ void k_scan(const int* __restrict__ counts, int* __restrict__ cursor,
                       float* __restrict__ dinv) {
    __shared__ int part[1024];
    int t = threadIdx.x;
    int base = t * 64;
    const int4* c4 = (const int4*)(counts + base);
    int4 loc[16];
    int s = 0;
#pragma unroll
    for (int i = 0; i < 16; ++i) {
        loc[i] = c4[i];
        s += loc[i].x + loc[i].y + loc[i].z + loc[i].w;
    }
    part[t] = s;
    __syncthreads();
    for (int off = 1; off < 1024; off <<= 1) {
        int val = (t >= off) ? part[t - off] : 0;
        __syncthreads();
        part[t] += val;
        __syncthreads();
    }
    int run = (t > 0) ? part[t - 1] : 0;   // exclusive offset of this thread's chunk
#pragma unroll
    for (int i = 0; i < 16; ++i) {
        int c0 = loc[i].x, c1 = loc[i].y, c2 = loc[i].z, c3 = loc[i].w;
        int j = base + i * 4;
        cursor[j]     = run;
        cursor[j + 1] = run + c0;
        cursor[j + 2] = run + c0 + c1;
        cursor[j + 3] = run + c0 + c1 + c2;
        dinv[j]     = rsqrtf((float)c0 + 1.0f);
        dinv[j + 1] = rsqrtf((float)c1 + 1.0f);
        dinv[j + 2] = rsqrtf((float)c2 + 1.0f);
        dinv[j + 3] = rsqrtf((float)c3 + 1.0f);
        run += c0 + c1 + c2 + c3;
    }
}

// Scatter src ids into CSR slots. Afterwards cursor[v] == row end.
__global__ void k_fill(const int* __restrict__ src, const int* __restrict__ dst,
                       int* __restrict__ cursor, int* __restrict__ csr) {
    int i = blockIdx.x * blockDim.x + threadIdx.x;
    int stride = gridDim.x * blockDim.x;
    for (int e = i; e < E_EDGES; e += stride) {
        int pos = atomicAdd(&cursor[dst[e]], 1);
        csr[pos] = src[e];
    }
}

// One thread per node. acc[64] in VGPRs; W[k][j] is wave-uniform -> scalar
// loads; h[v][k] per-lane float4. P[v] = dinv[v] * (h[v] @ W).
template <int F_K>
__global__ __launch_bounds__(256) void k_gemm_scale(
        const float* __restrict__ h, const float* __restrict__ W,
        const float* __restrict__ dinv, float* __restrict__ P) {
    int v = blockIdx.x * blockDim.x + threadIdx.x;
    const float4* hr = (const float4*)(h + (size_t)v * F_K);
    float4 acc[16];
#pragma unroll
    for (int j = 0; j < 16; ++j) acc[j] = make_float4(0.f, 0.f, 0.f, 0.f);
#pragma unroll 2
    for (int kb = 0; kb < F_K / 4; ++kb) {
        float4 hv = hr[kb];
#pragma unroll
        for (int r = 0; r < 4; ++r) {
            float hk = r == 0 ? hv.x : r == 1 ? hv.y : r == 2 ? hv.z : hv.w;
            const float4* Wr = (const float4*)(W + (size_t)(kb * 4 + r) * 64);
#pragma unroll
            for (int j = 0; j < 16; ++j) {
                float4 w = Wr[j];          // uniform across wave -> s_load
                acc[j].x = fmaf(hk, w.x, acc[j].x);
                acc[j].y = fmaf(hk, w.y, acc[j].y);
                acc[j].z = fmaf(hk, w.z, acc[j].z);
                acc[j].w = fmaf(hk, w.w, acc[j].w);
            }
        }
    }
    float s = dinv[v];
    float4* Pr = (float4*)(P + (size_t)v * 64);
#pragma unroll
    for (int j = 0; j < 16; ++j) {
        float4 a = acc[j];
        a.x *= s; a.y *= s; a.z *= s; a.w *= s;
        Pr[j] = a;
    }
}

// One 64-lane group per node: register-accumulate gathered P rows, write once.
template <bool RELU>
__global__ void k_aggregate(const float* __restrict__ P, const int* __restrict__ csr,
                            const int* __restrict__ cursor, const int* __restrict__ counts,
                            const float* __restrict__ dinv, const float* __restrict__ b,
                            float* __restrict__ out) {
    int lane = threadIdx.x & 63;
    int grp  = (blockIdx.x * blockDim.x + threadIdx.x) >> 6;
    int ngrp = (gridDim.x * blockDim.x) >> 6;
    float bias = b[lane];
    for (int v = grp; v < N_NODES; v += ngrp) {
        int end = cursor[v];
        int beg = end - counts[v];
        float acc = P[(size_t)v * 64 + lane];      // self loop
        int i = beg;
        for (; i + 3 < end; i += 4) {              // 4-deep ILP on the gather
            int s0 = csr[i], s1 = csr[i + 1], s2 = csr[i + 2], s3 = csr[i + 3];
            float p0 = P[(size_t)s0 * 64 + lane];
            float p1 = P[(size_t)s1 * 64 + lane];
            float p2 = P[(size_t)s2 * 64 + lane];
            float p3 = P[(size_t)s3 * 64 + lane];
            acc += (p0 + p1) + (p2 + p3);
        }
        for (; i < end; ++i)
            acc += P[(size_t)csr[i] * 64 + lane];
        float val = dinv[v] * acc + bias;
        if (RELU) val = val > 0.0f ? val : 0.0f;
        out[(size_t)v * 64 + lane] = val;
    }
}

extern "C" void kernel_launch(void* const* d_in, const int* in_sizes, int n_in,
                              void* d_out, int out_size, void* d_ws, size_t ws_size,
                              hipStream_t stream) {
    const float* x   = (const float*)d_in[0];
    const int*   ei  = (const int*)d_in[1];      // [2, E]: src row, dst row
    const float* W1  = (const float*)d_in[2];
    const float* b1  = (const float*)d_in[3];
    const float* W2  = (const float*)d_in[4];
    const float* b2  = (const float*)d_in[5];
    float*       out = (float*)d_out;

    const int* src = ei;
    const int* dst = ei + E_EDGES;

    float* dinv   = (float*)d_ws;                          // N floats
    int*   counts = (int*)(dinv + N_NODES);                // N ints
    int*   cursor = counts + N_NODES;                      // N ints
    int*   csr    = cursor + N_NODES;                      // E ints
    float* P      = (float*)(csr + E_EDGES);               // N*64 floats
    float* H      = out;                                   // layer-1 output lives in d_out

    // CSR build
    hipMemsetAsync(counts, 0, N_NODES * sizeof(int), stream);
    k_hist<<<1024, 256, 0, stream>>>(dst, counts);
    k_scan<<<1, 1024, 0, stream>>>(counts, cursor, dinv);
    k_fill<<<1024, 256, 0, stream>>>(src, dst, cursor, csr);

    // Layer 1: x -> H (relu)
    k_gemm_scale<F_IN><<<N_NODES / 256, 256, 0, stream>>>(x, W1, dinv, P);
    k_aggregate<true><<<2048, 256, 0, stream>>>(P, csr, cursor, counts, dinv, b1, H);

    // Layer 2: H -> out
    k_gemm_scale<F_HID><<<N_NODES / 256, 256, 0, stream>>>(H, W2, dinv, P);
    k_aggregate<false><<<2048, 256, 0, stream>>>(P, csr, cursor, counts, dinv, b2, out);
}

// Round 5
// 380.960 us; speedup vs baseline: 1.9176x; 1.0416x over previous
//
#include <hip/hip_runtime.h>

// GCN 2-layer, CSR-based (no fp32 atomics in the hot path).
//   counts[v] = # incoming edges (int hist, 1 thread/edge)
//   cursor    = exclusive prefix of counts; dinv = rsqrt(counts+1)
//   csr[pos]  = src, grouped by dst (fill advances cursor to end-of-row)
//   P = dinv * (h @ W)     (one thread per node, W via scalar loads)
//   out[v] = act(dinv[v] * (P[v] + sum_{e->v} P[src]) + b)
// Aggregate: one wave per node, 4 edges in flight (16-lane float4 subgroups),
// __shfl_xor butterfly to fold subgroup partials.

#define N_NODES 65536
#define E_EDGES 1048576
#define F_IN    128
#define F_HID   64

__global__ void k_hist(const int* __restrict__ dst, int* __restrict__ counts) {
    int e = blockIdx.x * blockDim.x + threadIdx.x;
    if (e < E_EDGES) atomicAdd(&counts[dst[e]], 1);
}

// One block, 1024 threads. Exclusive scan of counts -> cursor; dinv = rsqrt(c+1).
__global__ void k_scan(const int* __restrict__ counts, int* __restrict__ cursor,
                       float* __restrict__ dinv) {
    __shared__ int part[1024];
    int t = threadIdx.x;
    int base = t * 64;
    const int4* c4 = (const int4*)(counts + base);
    int4 loc[16];
    int s = 0;
#pragma unroll
    for (int i = 0; i < 16; ++i) {
        loc[i] = c4[i];
        s += loc[i].x + loc[i].y + loc[i].z + loc[i].w;
    }
    part[t] = s;
    __syncthreads();
    for (int off = 1; off < 1024; off <<= 1) {
        int val = (t >= off) ? part[t - off] : 0;
        __syncthreads();
        part[t] += val;
        __syncthreads();
    }
    int run = (t > 0) ? part[t - 1] : 0;   // exclusive offset of this thread's chunk
#pragma unroll
    for (int i = 0; i < 16; ++i) {
        int c0 = loc[i].x, c1 = loc[i].y, c2 = loc[i].z, c3 = loc[i].w;
        int j = base + i * 4;
        cursor[j]     = run;
        cursor[j + 1] = run + c0;
        cursor[j + 2] = run + c0 + c1;
        cursor[j + 3] = run + c0 + c1 + c2;
        dinv[j]     = rsqrtf((float)c0 + 1.0f);
        dinv[j + 1] = rsqrtf((float)c1 + 1.0f);
        dinv[j + 2] = rsqrtf((float)c2 + 1.0f);
        dinv[j + 3] = rsqrtf((float)c3 + 1.0f);
        run += c0 + c1 + c2 + c3;
    }
}

// Scatter src ids into CSR slots (1 thread/edge). Afterwards cursor[v] == row end.
__global__ void k_fill(const int* __restrict__ src, const int* __restrict__ dst,
                       int* __restrict__ cursor, int* __restrict__ csr) {
    int e = blockIdx.x * blockDim.x + threadIdx.x;
    if (e < E_EDGES) {
        int pos = atomicAdd(&cursor[dst[e]], 1);
        csr[pos] = src[e];
    }
}

// One thread per node. acc[64] in VGPRs; W[k][j] is wave-uniform -> scalar
// loads; h[v][k] per-lane float4. P[v] = dinv[v] * (h[v] @ W).
template <int F_K>
__global__ __launch_bounds__(256) void k_gemm_scale(
        const float* __restrict__ h, const float* __restrict__ W,
        const float* __restrict__ dinv, float* __restrict__ P) {
    int v = blockIdx.x * blockDim.x + threadIdx.x;
    const float4* hr = (const float4*)(h + (size_t)v * F_K);
    float4 acc[16];
#pragma unroll
    for (int j = 0; j < 16; ++j) acc[j] = make_float4(0.f, 0.f, 0.f, 0.f);
#pragma unroll 2
    for (int kb = 0; kb < F_K / 4; ++kb) {
        float4 hv = hr[kb];
#pragma unroll
        for (int r = 0; r < 4; ++r) {
            float hk = r == 0 ? hv.x : r == 1 ? hv.y : r == 2 ? hv.z : hv.w;
            const float4* Wr = (const float4*)(W + (size_t)(kb * 4 + r) * 64);
#pragma unroll
            for (int j = 0; j < 16; ++j) {
                float4 w = Wr[j];          // uniform across wave -> s_load
                acc[j].x = fmaf(hk, w.x, acc[j].x);
                acc[j].y = fmaf(hk, w.y, acc[j].y);
                acc[j].z = fmaf(hk, w.z, acc[j].z);
                acc[j].w = fmaf(hk, w.w, acc[j].w);
            }
        }
    }
    float s = dinv[v];
    float4* Pr = (float4*)(P + (size_t)v * 64);
#pragma unroll
    for (int j = 0; j < 16; ++j) {
        float4 a = acc[j];
        a.x *= s; a.y *= s; a.z *= s; a.w *= s;
        Pr[j] = a;
    }
}

// One wave per node; 4 edges in flight. Subgroup g = lanes [16g,16g+16) owns
// edge i+g and reads P[src] as float4 (16 lanes x 16B = full 256B row).
// Butterfly over subgroups at the end; lanes 0-15 write the result row.
template <bool RELU>
__global__ void k_aggregate(const float* __restrict__ P, const int* __restrict__ csr,
                            const int* __restrict__ cursor, const int* __restrict__ counts,
                            const float* __restrict__ dinv, const float* __restrict__ b,
                            float* __restrict__ out) {
    int lane = threadIdx.x & 63;
    int sub  = lane >> 4;              // which of the 4 in-flight edges
    int col4 = lane & 15;              // float4 column group
    int wave  = (blockIdx.x * blockDim.x + threadIdx.x) >> 6;
    int nwave = (gridDim.x * blockDim.x) >> 6;
    float4 bias = ((const float4*)b)[col4];
    for (int v = wave; v < N_NODES; v += nwave) {
        int end = cursor[v];
        int beg = end - counts[v];
        float4 acc = make_float4(0.f, 0.f, 0.f, 0.f);
        if (sub == 0)                  // self loop rides in subgroup 0
            acc = ((const float4*)(P + (size_t)v * 64))[col4];
        for (int i = beg; i < end; i += 4) {
            int e = i + sub;
            if (e < end) {
                int s = csr[e];
                float4 p = ((const float4*)(P + (size_t)s * 64))[col4];
                acc.x += p.x; acc.y += p.y; acc.z += p.z; acc.w += p.w;
            }
        }
        // fold the 4 subgroup partials: xor 16 then xor 32
        acc.x += __shfl_xor(acc.x, 16); acc.y += __shfl_xor(acc.y, 16);
        acc.z += __shfl_xor(acc.z, 16); acc.w += __shfl_xor(acc.w, 16);
        acc.x += __shfl_xor(acc.x, 32); acc.y += __shfl_xor(acc.y, 32);
        acc.z += __shfl_xor(acc.z, 32); acc.w += __shfl_xor(acc.w, 32);
        if (lane < 16) {
            float s = dinv[v];
            float4 o;
            o.x = s * acc.x + bias.x;
            o.y = s * acc.y + bias.y;
            o.z = s * acc.z + bias.z;
            o.w = s * acc.w + bias.w;
            if (RELU) {
                o.x = o.x > 0.f ? o.x : 0.f;
                o.y = o.y > 0.f ? o.y : 0.f;
                o.z = o.z > 0.f ? o.z : 0.f;
                o.w = o.w > 0.f ? o.w : 0.f;
            }
            ((float4*)(out + (size_t)v * 64))[col4] = o;
        }
    }
}

extern "C" void kernel_launch(void* const* d_in, const int* in_sizes, int n_in,
                              void* d_out, int out_size, void* d_ws, size_t ws_size,
                              hipStream_t stream) {
    const float* x   = (const float*)d_in[0];
    const int*   ei  = (const int*)d_in[1];      // [2, E]: src row, dst row
    const float* W1  = (const float*)d_in[2];
    const float* b1  = (const float*)d_in[3];
    const float* W2  = (const float*)d_in[4];
    const float* b2  = (const float*)d_in[5];
    float*       out = (float*)d_out;

    const int* src = ei;
    const int* dst = ei + E_EDGES;

    float* dinv   = (float*)d_ws;                          // N floats
    int*   counts = (int*)(dinv + N_NODES);                // N ints
    int*   cursor = counts + N_NODES;                      // N ints
    int*   csr    = cursor + N_NODES;                      // E ints
    float* P      = (float*)(csr + E_EDGES);               // N*64 floats
    float* H      = out;                                   // layer-1 output lives in d_out

    // CSR build
    hipMemsetAsync(counts, 0, N_NODES * sizeof(int), stream);
    k_hist<<<E_EDGES / 256, 256, 0, stream>>>(dst, counts);
    k_scan<<<1, 1024, 0, stream>>>(counts, cursor, dinv);
    k_fill<<<E_EDGES / 256, 256, 0, stream>>>(src, dst, cursor, csr);

    // Layer 1: x -> H (relu)
    k_gemm_scale<F_IN><<<N_NODES / 256, 256, 0, stream>>>(x, W1, dinv, P);
    k_aggregate<true><<<4096, 256, 0, stream>>>(P, csr, cursor, counts, dinv, b1, H);

    // Layer 2: H -> out
    k_gemm_scale<F_HID><<<N_NODES / 256, 256, 0, stream>>>(H, W2, dinv, P);
    k_aggregate<false><<<4096, 256, 0, stream>>>(P, csr, cursor, counts, dinv, b2, out);
}

// Round 6
// 282.590 us; speedup vs baseline: 2.5851x; 1.3481x over previous
//
#include <hip/hip_runtime.h>

// GCN 2-layer, padded-CSR (CAP=64 slots/node), no hist/scan passes.
//   fill (XCD-partitioned): cnt[dst]++, csr[dst*64 + pos] = src
//   P = rsqrt(cnt+1) * (h @ W)     (one thread per node, W via scalar loads)
//   out[v] = act(rsqrt(cnt[v]+1) * (P[v] + sum_in P[src]) + b)
// Fill partitioning: group g = blockIdx&7 (XCD round-robin heuristic) owns
// dst range [g*8192, (g+1)*8192) so each csr line is written by one L2 only
// -> full-line writebacks instead of 18x write amplification.

#define N_NODES 65536
#define E_EDGES 1048576
#define F_IN    128
#define F_HID   64
#define CAPSH   6            // 64 slots per node
 
// 8 groups x 1024 chunks; thread handles 4 edges via int4 dst load.
__global__ __launch_bounds__(256) void k_fill(
        const int* __restrict__ src, const int* __restrict__ dst,
        int* __restrict__ cnt, int* __restrict__ csr) {
    int g     = blockIdx.x & 7;
    int chunk = blockIdx.x >> 3;
    int i     = chunk * blockDim.x + threadIdx.x;      // int4 index
    int4 d = ((const int4*)dst)[i];
#pragma unroll
    for (int k = 0; k < 4; ++k) {
        int dv = k == 0 ? d.x : k == 1 ? d.y : k == 2 ? d.z : d.w;
        if ((dv >> 13) == g) {
            int pos = atomicAdd(&cnt[dv], 1);
            csr[(dv << CAPSH) + pos] = src[4 * i + k];
        }
    }
}

// One thread per node. acc[64] in VGPRs; W[k][j] wave-uniform -> scalar
// loads; h[v][k] per-lane float4. P[v] = rsqrt(cnt[v]+1) * (h[v] @ W).
template <int F_K>
__global__ __launch_bounds__(256) void k_gemm_scale(
        const float* __restrict__ h, const float* __restrict__ W,
        const int* __restrict__ cnt, float* __restrict__ P) {
    int v = blockIdx.x * blockDim.x + threadIdx.x;
    const float4* hr = (const float4*)(h + (size_t)v * F_K);
    float4 acc[16];
#pragma unroll
    for (int j = 0; j < 16; ++j) acc[j] = make_float4(0.f, 0.f, 0.f, 0.f);
#pragma unroll 2
    for (int kb = 0; kb < F_K / 4; ++kb) {
        float4 hv = hr[kb];
#pragma unroll
        for (int r = 0; r < 4; ++r) {
            float hk = r == 0 ? hv.x : r == 1 ? hv.y : r == 2 ? hv.z : hv.w;
            const float4* Wr = (const float4*)(W + (size_t)(kb * 4 + r) * 64);
#pragma unroll
            for (int j = 0; j < 16; ++j) {
                float4 w = Wr[j];          // uniform across wave -> s_load
                acc[j].x = fmaf(hk, w.x, acc[j].x);
                acc[j].y = fmaf(hk, w.y, acc[j].y);
                acc[j].z = fmaf(hk, w.z, acc[j].z);
                acc[j].w = fmaf(hk, w.w, acc[j].w);
            }
        }
    }
    float s = rsqrtf((float)cnt[v] + 1.0f);
    float4* Pr = (float4*)(P + (size_t)v * 64);
#pragma unroll
    for (int j = 0; j < 16; ++j) {
        float4 a = acc[j];
        a.x *= s; a.y *= s; a.z *= s; a.w *= s;
        Pr[j] = a;
    }
}

// One wave per node; 4 edges in flight. Subgroup g = lanes [16g,16g+16) owns
// edge i+g and reads P[src] as float4 (16 lanes x 16B = full 256B row).
// Butterfly over subgroups at the end; lanes 0-15 write the result row.
template <bool RELU>
__global__ void k_aggregate(const float* __restrict__ P, const int* __restrict__ csr,
                            const int* __restrict__ cnt, const float* __restrict__ b,
                            float* __restrict__ out) {
    int lane = threadIdx.x & 63;
    int sub  = lane >> 4;              // which of the 4 in-flight edges
    int col4 = lane & 15;              // float4 column group
    int wave  = (blockIdx.x * blockDim.x + threadIdx.x) >> 6;
    int nwave = (gridDim.x * blockDim.x) >> 6;
    float4 bias = ((const float4*)b)[col4];
    for (int v = wave; v < N_NODES; v += nwave) {
        int c   = cnt[v];
        int beg = v << CAPSH;
        float4 acc = make_float4(0.f, 0.f, 0.f, 0.f);
        if (sub == 0)                  // self loop rides in subgroup 0
            acc = ((const float4*)(P + (size_t)v * 64))[col4];
        for (int i = 0; i < c; i += 4) {
            int e = i + sub;
            if (e < c) {
                int s = csr[beg + e];
                float4 p = ((const float4*)(P + (size_t)s * 64))[col4];
                acc.x += p.x; acc.y += p.y; acc.z += p.z; acc.w += p.w;
            }
        }
        // fold the 4 subgroup partials: xor 16 then xor 32
        acc.x += __shfl_xor(acc.x, 16); acc.y += __shfl_xor(acc.y, 16);
        acc.z += __shfl_xor(acc.z, 16); acc.w += __shfl_xor(acc.w, 16);
        acc.x += __shfl_xor(acc.x, 32); acc.y += __shfl_xor(acc.y, 32);
        acc.z += __shfl_xor(acc.z, 32); acc.w += __shfl_xor(acc.w, 32);
        if (lane < 16) {
            float s = rsqrtf((float)c + 1.0f);
            float4 o;
            o.x = s * acc.x + bias.x;
            o.y = s * acc.y + bias.y;
            o.z = s * acc.z + bias.z;
            o.w = s * acc.w + bias.w;
            if (RELU) {
                o.x = o.x > 0.f ? o.x : 0.f;
                o.y = o.y > 0.f ? o.y : 0.f;
                o.z = o.z > 0.f ? o.z : 0.f;
                o.w = o.w > 0.f ? o.w : 0.f;
            }
            ((float4*)(out + (size_t)v * 64))[col4] = o;
        }
    }
}

extern "C" void kernel_launch(void* const* d_in, const int* in_sizes, int n_in,
                              void* d_out, int out_size, void* d_ws, size_t ws_size,
                              hipStream_t stream) {
    const float* x   = (const float*)d_in[0];
    const int*   ei  = (const int*)d_in[1];      // [2, E]: src row, dst row
    const float* W1  = (const float*)d_in[2];
    const float* b1  = (const float*)d_in[3];
    const float* W2  = (const float*)d_in[4];
    const float* b2  = (const float*)d_in[5];
    float*       out = (float*)d_out;

    const int* src = ei;
    const int* dst = ei + E_EDGES;

    int*   cnt = (int*)d_ws;                               // N ints
    int*   csr = cnt + N_NODES;                            // N*64 ints (16MB)
    float* P   = (float*)(csr + ((size_t)N_NODES << CAPSH)); // N*64 floats (16MB)
    float* H   = out;                                      // layer-1 output in d_out

    // Padded-CSR build (single pass; cnt doubles as degree)
    hipMemsetAsync(cnt, 0, N_NODES * sizeof(int), stream);
    k_fill<<<(E_EDGES / 4 / 256) * 8, 256, 0, stream>>>(src, dst, cnt, csr);

    // Layer 1: x -> H (relu)
    k_gemm_scale<F_IN><<<N_NODES / 256, 256, 0, stream>>>(x, W1, cnt, P);
    k_aggregate<true><<<4096, 256, 0, stream>>>(P, csr, cnt, b1, H);

    // Layer 2: H -> out
    k_gemm_scale<F_HID><<<N_NODES / 256, 256, 0, stream>>>(H, W2, cnt, P);
    k_aggregate<false><<<4096, 256, 0, stream>>>(P, csr, cnt, b2, out);
}

// Round 7
// 254.101 us; speedup vs baseline: 2.8750x; 1.1121x over previous
//
#include <hip/hip_runtime.h>

// GCN 2-layer, padded-CSR (CAP=64 slots/node), no hist/scan passes.
//   fill (XCD-partitioned): cnt[dst]++, csr[dst*64 + pos] = src
//   P = rsqrt(cnt+1) * (h @ W)
//   out[v] = act(rsqrt(cnt[v]+1) * (P[v] + sum_in P[src]) + b)
// GEMM: block = 64 nodes x 4 col-blocks. Wave w computes cols [16w,16w+16)
// for 64 nodes -> W addresses wave-uniform (s_load), 4 waves/SIMD occupancy.

#define N_NODES 65536
#define E_EDGES 1048576
#define F_IN    128
#define F_HID   64
#define CAPSH   6            // 64 slots per node

// 8 groups x 1024 chunks; thread handles 4 edges via int4 dst load.
__global__ __launch_bounds__(256) void k_fill(
        const int* __restrict__ src, const int* __restrict__ dst,
        int* __restrict__ cnt, int* __restrict__ csr) {
    int g     = blockIdx.x & 7;
    int chunk = blockIdx.x >> 3;
    int i     = chunk * blockDim.x + threadIdx.x;      // int4 index
    int4 d = ((const int4*)dst)[i];
#pragma unroll
    for (int k = 0; k < 4; ++k) {
        int dv = k == 0 ? d.x : k == 1 ? d.y : k == 2 ? d.z : d.w;
        if ((dv >> 13) == g) {
            int pos = atomicAdd(&cnt[dv], 1);
            csr[(dv << CAPSH) + pos] = src[4 * i + k];
        }
    }
}

// Block = 64 nodes x 4 waves. Wave w: cols [16w, 16w+16) of all 64 nodes.
// W[k][16w+j] wave-uniform -> scalar loads; h[v][k] per-lane float4.
// P[v] = rsqrt(cnt[v]+1) * (h[v] @ W).
template <int F_K>
__global__ __launch_bounds__(256) void k_gemm_scale(
        const float* __restrict__ h, const float* __restrict__ W,
        const int* __restrict__ cnt, float* __restrict__ P) {
    int wave = __builtin_amdgcn_readfirstlane(threadIdx.x >> 6);  // 0..3, SGPR
    int lane = threadIdx.x & 63;
    int v = blockIdx.x * 64 + lane;
    const float4* hr = (const float4*)(h + (size_t)v * F_K);
    float4 acc[4];
#pragma unroll
    for (int j = 0; j < 4; ++j) acc[j] = make_float4(0.f, 0.f, 0.f, 0.f);
#pragma unroll 4
    for (int kb = 0; kb < F_K / 4; ++kb) {
        float4 hv = hr[kb];
#pragma unroll
        for (int r = 0; r < 4; ++r) {
            float hk = r == 0 ? hv.x : r == 1 ? hv.y : r == 2 ? hv.z : hv.w;
            const float4* Wr = (const float4*)(W + (size_t)(kb * 4 + r) * 64 + (wave << 4));
#pragma unroll
            for (int j = 0; j < 4; ++j) {
                float4 w = Wr[j];          // uniform across wave -> s_load
                acc[j].x = fmaf(hk, w.x, acc[j].x);
                acc[j].y = fmaf(hk, w.y, acc[j].y);
                acc[j].z = fmaf(hk, w.z, acc[j].z);
                acc[j].w = fmaf(hk, w.w, acc[j].w);
            }
        }
    }
    float s = rsqrtf((float)cnt[v] + 1.0f);
    float4* Pr = (float4*)(P + (size_t)v * 64 + (wave << 4));
#pragma unroll
    for (int j = 0; j < 4; ++j) {
        float4 a = acc[j];
        a.x *= s; a.y *= s; a.z *= s; a.w *= s;
        Pr[j] = a;
    }
}

// One wave per node; 4 edges in flight. Subgroup g = lanes [16g,16g+16) owns
// edge i+g and reads P[src] as float4 (16 lanes x 16B = full 256B row).
// Butterfly over subgroups at the end; lanes 0-15 write the result row.
template <bool RELU>
__global__ void k_aggregate(const float* __restrict__ P, const int* __restrict__ csr,
                            const int* __restrict__ cnt, const float* __restrict__ b,
                            float* __restrict__ out) {
    int lane = threadIdx.x & 63;
    int sub  = lane >> 4;              // which of the 4 in-flight edges
    int col4 = lane & 15;              // float4 column group
    int wave  = (blockIdx.x * blockDim.x + threadIdx.x) >> 6;
    int nwave = (gridDim.x * blockDim.x) >> 6;
    float4 bias = ((const float4*)b)[col4];
    for (int v = wave; v < N_NODES; v += nwave) {
        int c   = cnt[v];
        int beg = v << CAPSH;
        float4 acc = make_float4(0.f, 0.f, 0.f, 0.f);
        if (sub == 0)                  // self loop rides in subgroup 0
            acc = ((const float4*)(P + (size_t)v * 64))[col4];
        for (int i = 0; i < c; i += 4) {
            int e = i + sub;
            if (e < c) {
                int s = csr[beg + e];
                float4 p = ((const float4*)(P + (size_t)s * 64))[col4];
                acc.x += p.x; acc.y += p.y; acc.z += p.z; acc.w += p.w;
            }
        }
        // fold the 4 subgroup partials: xor 16 then xor 32
        acc.x += __shfl_xor(acc.x, 16); acc.y += __shfl_xor(acc.y, 16);
        acc.z += __shfl_xor(acc.z, 16); acc.w += __shfl_xor(acc.w, 16);
        acc.x += __shfl_xor(acc.x, 32); acc.y += __shfl_xor(acc.y, 32);
        acc.z += __shfl_xor(acc.z, 32); acc.w += __shfl_xor(acc.w, 32);
        if (lane < 16) {
            float s = rsqrtf((float)c + 1.0f);
            float4 o;
            o.x = s * acc.x + bias.x;
            o.y = s * acc.y + bias.y;
            o.z = s * acc.z + bias.z;
            o.w = s * acc.w + bias.w;
            if (RELU) {
                o.x = o.x > 0.f ? o.x : 0.f;
                o.y = o.y > 0.f ? o.y : 0.f;
                o.z = o.z > 0.f ? o.z : 0.f;
                o.w = o.w > 0.f ? o.w : 0.f;
            }
            ((float4*)(out + (size_t)v * 64))[col4] = o;
        }
    }
}

extern "C" void kernel_launch(void* const* d_in, const int* in_sizes, int n_in,
                              void* d_out, int out_size, void* d_ws, size_t ws_size,
                              hipStream_t stream) {
    const float* x   = (const float*)d_in[0];
    const int*   ei  = (const int*)d_in[1];      // [2, E]: src row, dst row
    const float* W1  = (const float*)d_in[2];
    const float* b1  = (const float*)d_in[3];
    const float* W2  = (const float*)d_in[4];
    const float* b2  = (const float*)d_in[5];
    float*       out = (float*)d_out;

    const int* src = ei;
    const int* dst = ei + E_EDGES;

    int*   cnt = (int*)d_ws;                               // N ints
    int*   csr = cnt + N_NODES;                            // N*64 ints (16MB)
    float* P   = (float*)(csr + ((size_t)N_NODES << CAPSH)); // N*64 floats (16MB)
    float* H   = out;                                      // layer-1 output in d_out

    // Padded-CSR build (single pass; cnt doubles as degree)
    hipMemsetAsync(cnt, 0, N_NODES * sizeof(int), stream);
    k_fill<<<(E_EDGES / 4 / 256) * 8, 256, 0, stream>>>(src, dst, cnt, csr);

    // Layer 1: x -> H (relu)
    k_gemm_scale<F_IN><<<N_NODES / 64, 256, 0, stream>>>(x, W1, cnt, P);
    k_aggregate<true><<<4096, 256, 0, stream>>>(P, csr, cnt, b1, H);

    // Layer 2: H -> out
    k_gemm_scale<F_HID><<<N_NODES / 64, 256, 0, stream>>>(H, W2, cnt, P);
    k_aggregate<false><<<4096, 256, 0, stream>>>(P, csr, cnt, b2, out);
}